// Round 1
// baseline (1907.212 us; speedup 1.0000x reference)
//
#include <hip/hip_runtime.h>
#include <hip/hip_bf16.h>

// ---------------------------------------------------------------------------
// Segment_3DCenter: fp32 implementation.
// Layouts:
//   x_t   [b][p][d]        (64,121,128)   transposed input (d = original C)
//   sa_t  [b][oc][p][d]    (64,16,121,128) conv3d outputs (bufA/bufB ping-pong)
//   f_all [i][b][oc][p]    (5,64,16,121)  the five 2D feature maps
//   sp_sd [i][b][o]        (5,64,16)      sp side outputs
// ---------------------------------------------------------------------------

#define F_SLICE (64 * 16 * 121)  // 123904

// ---------------- transpose x: [b][c][p] -> [b][p][c] ----------------------
__global__ __launch_bounds__(128) void transpose_kernel(
    const float* __restrict__ x, float* __restrict__ x_t) {
  int b = blockIdx.x, t = threadIdx.x;
  if (t < 121) {
    for (int c = 0; c < 128; ++c)
      x_t[((size_t)b * 121 + t) * 128 + c] = x[((size_t)b * 128 + c) * 121 + t];
  }
}

// ---------------- softmax over last dim of cpr_w (48 rows x 128) -----------
__global__ __launch_bounds__(128) void softmax_kernel(
    const float* __restrict__ w, float* __restrict__ a) {
  int row = blockIdx.x, t = threadIdx.x;
  __shared__ float red[128];
  float v = w[row * 128 + t];
  red[t] = v;
  __syncthreads();
  for (int s = 64; s; s >>= 1) {
    if (t < s) red[t] = fmaxf(red[t], red[t + s]);
    __syncthreads();
  }
  float m = red[0];
  __syncthreads();
  float e = expf(v - m);
  red[t] = e;
  __syncthreads();
  for (int s = 64; s; s >>= 1) {
    if (t < s) red[t] += red[t + s];
    __syncthreads();
  }
  a[row * 128 + t] = e / red[0];
}

// ---------------- conv3d (7x3x3, pad 3/1/1) + bias + relu ------------------
// in  [b][IC][p][d], wgt [16][IC][7][3][3], out [b][16][p][d]
// block: 256 thr = 4 waves; wave&1 -> d-half, wave>>1 -> oc-half (8 oc)
// each thread: 8 oc x 2 adjacent-w pixels accumulators.
template <int IC>
__global__ __launch_bounds__(256, 2) void conv3d_kernel(
    const float* __restrict__ in, const float* __restrict__ wgt,
    const float* __restrict__ bias, float* __restrict__ outp) {
  constexpr int ICC = (IC == 16) ? 8 : 1;
  __shared__ float in_lds[ICC][12][134];  // [ic][3h x 4w][dpad]
  const int t = threadIdx.x;
  const int pr = blockIdx.x;  // 0..65
  const int b = blockIdx.y;
  const int h = pr / 6;
  const int w0 = (pr % 6) * 2;
  const int lane = t & 63;
  const int wv = t >> 6;
  const int dd = lane + ((wv & 1) << 6);  // 0..127
  const int oc_base = __builtin_amdgcn_readfirstlane((wv >> 1) << 3);

  float acc[8][2];
#pragma unroll
  for (int o = 0; o < 8; ++o) { acc[o][0] = 0.f; acc[o][1] = 0.f; }

  for (int ic0 = 0; ic0 < IC; ic0 += ICC) {
    __syncthreads();
    // stage ICC*12 rows of 134 (zero-padded depth + spatial halo)
    for (int r = (t >> 7); r < ICC * 12; r += 2) {
      int ic = r / 12;
      int sp = r - ic * 12;
      int hh = h - 1 + (sp >> 2);
      int ww = w0 - 1 + (sp & 3);
      bool ok = (hh >= 0) & (hh < 11) & (ww >= 0) & (ww < 11);
      const float* src =
          in + (((size_t)b * IC + ic0 + ic) * 121 + hh * 11 + ww) * 128;
      int ds = t & 127;
      float v = 0.f;
      int di = ds - 3;
      if (ok && di >= 0 && di < 128) v = src[di];
      in_lds[ic][sp][ds] = v;
      if (ds < 6) {
        float v2 = 0.f;
        int dj = 125 + ds;
        if (ok && dj < 128) v2 = src[dj];
        in_lds[ic][sp][128 + ds] = v2;
      }
    }
    __syncthreads();
    for (int ic = 0; ic < ICC; ++ic) {
      const float* wp = wgt + ((size_t)oc_base * IC + ic0 + ic) * 63;
#pragma unroll
      for (int kd = 0; kd < 7; ++kd) {
#pragma unroll
        for (int kh = 0; kh < 3; ++kh) {
#pragma unroll
          for (int kw = 0; kw < 3; ++kw) {
            float v0 = in_lds[ic][(kh << 2) + kw][dd + kd];
            float v1 = in_lds[ic][(kh << 2) + kw + 1][dd + kd];
            const int widx = kd * 9 + kh * 3 + kw;
#pragma unroll
            for (int o = 0; o < 8; ++o) {
              float wv_ = wp[(size_t)o * IC * 63 + widx];  // wave-uniform -> s_load
              acc[o][0] = fmaf(wv_, v0, acc[o][0]);
              acc[o][1] = fmaf(wv_, v1, acc[o][1]);
            }
          }
        }
      }
    }
  }
  const int p0 = h * 11 + w0;
#pragma unroll
  for (int o = 0; o < 8; ++o) {
    float bv = bias[oc_base + o];
    outp[(((size_t)b * 16 + oc_base + o) * 121 + p0) * 128 + dd] =
        fmaxf(acc[o][0] + bv, 0.f);
    if (w0 + 1 < 11)
      outp[(((size_t)b * 16 + oc_base + o) * 121 + p0 + 1) * 128 + dd] =
          fmaxf(acc[o][1] + bv, 0.f);
  }
}

// ---------------- cpr: f[row] = relu(sum_d sa[row][d] * a[oc][d]) ----------
__global__ __launch_bounds__(256) void cpr_kernel(
    const float* __restrict__ sa, const float* __restrict__ al,
    float* __restrict__ fo) {
  int wid = (blockIdx.x * 256 + threadIdx.x) >> 6;
  int lane = threadIdx.x & 63;
  const int nw = 512 * 4;
  for (int row = wid; row < F_SLICE; row += nw) {
    int oc = (row / 121) & 15;
    const float* s = sa + (size_t)row * 128;
    const float* aa = al + oc * 128;
    float v = s[lane] * aa[lane] + s[lane + 64] * aa[lane + 64];
#pragma unroll
    for (int off = 32; off; off >>= 1) v += __shfl_down(v, off, 64);
    if (lane == 0) fo[row] = fmaxf(v, 0.f);
  }
}

// ---------------- 16->16 2D conv 3x3 pad1 + relu (one block per b) ---------
__global__ __launch_bounds__(128) void conv2d_kernel(
    const float* __restrict__ fin, const float* __restrict__ wgt,
    const float* __restrict__ bias, float* __restrict__ fout) {
  const int b = blockIdx.x, t = threadIdx.x;
  __shared__ float fl[16 * 121];
  const float* fb = fin + (size_t)b * 16 * 121;
  for (int idx = t; idx < 16 * 121; idx += 128) fl[idx] = fb[idx];
  __syncthreads();
  if (t < 121) {
    int h = t / 11, w = t - h * 11;
    float acc[16];
#pragma unroll
    for (int o = 0; o < 16; ++o) acc[o] = bias[o];
    for (int ic = 0; ic < 16; ++ic) {
#pragma unroll
      for (int u = 0; u < 3; ++u) {
        int hh = h + u - 1;
#pragma unroll
        for (int v = 0; v < 3; ++v) {
          int ww = w + v - 1;
          float val = (hh >= 0 && hh < 11 && ww >= 0 && ww < 11)
                          ? fl[ic * 121 + hh * 11 + ww]
                          : 0.f;
          const float* wp = wgt + ic * 9 + u * 3 + v;
#pragma unroll
          for (int o = 0; o < 16; ++o) acc[o] = fmaf(val, wp[o * 144], acc[o]);
        }
      }
    }
    float* ob = fout + (size_t)b * 16 * 121;
#pragma unroll
    for (int o = 0; o < 16; ++o) ob[o * 121 + t] = fmaxf(acc[o], 0.f);
  }
}

// ---------------- sp path: seg conv -> top5 -> s7 -> patch convs -> side ---
// One block per (b, i). Only the 7x7 img patch (global rows/cols 61..67)
// influences the center pixel of the final dilated conv -> side output.
__global__ __launch_bounds__(128) void sp_prep_kernel(
    const float* __restrict__ f_all, const float* __restrict__ x_t,
    const float* __restrict__ seg_w, const float* __restrict__ seg_b,
    const float* __restrict__ sp_wa, const float* __restrict__ sp_ba,
    const float* __restrict__ sp_wb, const float* __restrict__ sp_bb,
    const float* __restrict__ sp_sw, const float* __restrict__ sp_sb,
    float* __restrict__ sp_sd) {
  const int b = blockIdx.x, i = blockIdx.y;
  const int t = threadIdx.x;
  __shared__ float fl[16 * 121];
  __shared__ float act[121];
  __shared__ float diffs[121];
  __shared__ int sel[5];
  __shared__ float s7[7], xc7[7];
  __shared__ float P[2][7][7];
  __shared__ float y1[16][9];
  __shared__ float y2[16];

  const float* fb = f_all + ((size_t)i * 64 + b) * 16 * 121;
  for (int idx = t; idx < 16 * 121; idx += 128) fl[idx] = fb[idx];
  __syncthreads();

  // seg conv (no relu): act[p]
  if (t < 121) {
    int h = t / 11, w = t - h * 11;
    float a = seg_b[i];
    const float* sw = seg_w + i * 144;
#pragma unroll
    for (int u = 0; u < 3; ++u) {
      int hh = h + u - 1;
#pragma unroll
      for (int v = 0; v < 3; ++v) {
        int ww = w + v - 1;
        if (hh >= 0 && hh < 11 && ww >= 0 && ww < 11) {
          int pp = hh * 11 + ww;
          for (int ic = 0; ic < 16; ++ic)
            a = fmaf(fl[ic * 121 + pp], sw[ic * 9 + u * 3 + v], a);
        }
      }
    }
    act[t] = a;
  }
  __syncthreads();
  if (t < 121) diffs[t] = fabsf(act[t] - act[60]);
  __syncthreads();

  // 5x argmin with tie -> lowest index (matches jax.lax.top_k on -diff)
  for (int k = 0; k < 5; ++k) {
    if (t < 64) {
      float d0 = diffs[t];
      int i0 = t;
      float d1 = (t + 64 < 121) ? diffs[t + 64] : 3.0e38f;
      if (d1 < d0) { d0 = d1; i0 = t + 64; }
#pragma unroll
      for (int off = 32; off; off >>= 1) {
        float od = __shfl_down(d0, off, 64);
        int oi = __shfl_down(i0, off, 64);
        if (od < d0 || (od == d0 && oi < i0)) { d0 = od; i0 = oi; }
      }
      if (t == 0) {
        sel[k] = i0;
        diffs[i0] = 3.0e38f;
      }
    }
    __syncthreads();
  }

  // s over channels 61..67; center-x channels 61..67
  if (t < 7) {
    const float* xb = x_t + (size_t)b * 121 * 128;
    float s = 0.f;
    for (int k = 0; k < 5; ++k) s += xb[(size_t)sel[k] * 128 + 61 + t];
    s7[t] = s;
    xc7[t] = xb[60 * 128 + 61 + t];
  }
  __syncthreads();
  // img patch: P[0] = ratio(s), P[1] = ratio(center(x)); rows/cols 61..67
  if (t < 49) {
    int r = t / 7, c = t - r * 7;
    float d0 = s7[c];
    if (fabsf(d0) < 0.01f) d0 = 0.01f;
    float d1 = xc7[c];
    if (fabsf(d1) < 0.01f) d1 = 0.01f;
    P[0][r][c] = s7[r] / d0;
    P[1][r][c] = xc7[r] / d1;
  }
  __syncthreads();
  // conv1 (3x3, pad irrelevant - interior): y1 at patch pos (1+2a, 1+2b)
  for (int item = t; item < 144; item += 128) {
    int ch = item / 9, pos = item - ch * 9;
    int a0 = pos / 3, b0 = pos - a0 * 3;
    float a = sp_ba[i * 16 + ch];
    const float* wa = sp_wa + ((size_t)(i * 16 + ch) * 2) * 9;
#pragma unroll
    for (int icc = 0; icc < 2; ++icc)
#pragma unroll
      for (int u = 0; u < 3; ++u)
#pragma unroll
        for (int v = 0; v < 3; ++v)
          a = fmaf(P[icc][2 * a0 + u][2 * b0 + v], wa[icc * 9 + u * 3 + v], a);
    y1[ch][pos] = fmaxf(a, 0.f);
  }
  __syncthreads();
  // conv2 (3x3 dil=2) at center only
  if (t < 16) {
    float a = sp_bb[i * 16 + t];
    const float* wb = sp_wb + (size_t)(i * 16 + t) * 16 * 9;
    for (int ch = 0; ch < 16; ++ch)
#pragma unroll
      for (int pos = 0; pos < 9; ++pos) a = fmaf(y1[ch][pos], wb[ch * 9 + pos], a);
    y2[t] = fmaxf(a, 0.f);
  }
  __syncthreads();
  if (t < 16) {
    float a = sp_sb[i * 16 + t];
    const float* swp = sp_sw + (size_t)(i * 16 + t) * 16;
    for (int ch = 0; ch < 16; ++ch) a = fmaf(y2[ch], swp[ch], a);
    sp_sd[((size_t)i * 64 + b) * 16 + t] = a;
  }
}

// ---------------- final fuse: sa sides + sp sides --------------------------
__global__ __launch_bounds__(256) void fuse_kernel(
    const float* __restrict__ f_all, const float* __restrict__ sp_sd,
    const float* __restrict__ so_w, const float* __restrict__ so_b,
    const float* __restrict__ fp, float* __restrict__ out) {
  int g = blockIdx.x * 256 + threadIdx.x;
  if (g >= 1024) return;
  int b = g >> 4, o = g & 15;
  float tot = 0.f;
  for (int i = 0; i < 5; ++i) {
    float s = so_b[i * 16 + o];
    for (int c = 0; c < 16; ++c)
      s += f_all[(((size_t)i * 64 + b) * 16 + c) * 121 + 60] *
           so_w[(i * 16 + o) * 16 + c];
    tot += fp[i] * s;
    tot += fp[5 + i] * sp_sd[((size_t)i * 64 + b) * 16 + o];
  }
  out[g] = tot;
}

extern "C" void kernel_launch(void* const* d_in, const int* in_sizes, int n_in,
                              void* d_out, int out_size, void* d_ws,
                              size_t ws_size, hipStream_t stream) {
  const float* x = (const float*)d_in[0];
  const float* w3d1 = (const float*)d_in[1];
  const float* b3d1 = (const float*)d_in[2];
  const float* w3d23 = (const float*)d_in[3];
  const float* b3d23 = (const float*)d_in[4];
  const float* cpr_w = (const float*)d_in[5];
  const float* w2d45 = (const float*)d_in[6];
  const float* b2d45 = (const float*)d_in[7];
  const float* seg_w = (const float*)d_in[8];
  const float* seg_b = (const float*)d_in[9];
  const float* so_w = (const float*)d_in[10];
  const float* so_b = (const float*)d_in[11];
  const float* sp_wa = (const float*)d_in[12];
  const float* sp_ba = (const float*)d_in[13];
  const float* sp_wb = (const float*)d_in[14];
  const float* sp_bb = (const float*)d_in[15];
  const float* sp_sw = (const float*)d_in[16];
  const float* sp_sb = (const float*)d_in[17];
  const float* fpar = (const float*)d_in[18];

  float* ws = (float*)d_ws;
  float* x_t = ws;                      // 991232
  float* bufA = x_t + 991232;           // 15859712
  float* bufB = bufA + 15859712;        // 15859712
  float* a_sm = bufB + 15859712;        // 6144
  float* f_all = a_sm + 6144;           // 619520
  float* sp_sd = f_all + 619520;        // 5120

  transpose_kernel<<<64, 128, 0, stream>>>(x, x_t);
  softmax_kernel<<<48, 128, 0, stream>>>(cpr_w, a_sm);

  conv3d_kernel<1><<<dim3(66, 64), 256, 0, stream>>>(x_t, w3d1, b3d1, bufA);
  cpr_kernel<<<512, 256, 0, stream>>>(bufA, a_sm, f_all);

  conv3d_kernel<16><<<dim3(66, 64), 256, 0, stream>>>(bufA, w3d23, b3d23, bufB);
  cpr_kernel<<<512, 256, 0, stream>>>(bufB, a_sm + 2048, f_all + F_SLICE);

  conv3d_kernel<16><<<dim3(66, 64), 256, 0, stream>>>(bufB, w3d23 + 16128,
                                                      b3d23 + 16, bufA);
  cpr_kernel<<<512, 256, 0, stream>>>(bufA, a_sm + 4096, f_all + 2 * F_SLICE);

  conv2d_kernel<<<64, 128, 0, stream>>>(f_all + 2 * F_SLICE, w2d45, b2d45,
                                        f_all + 3 * F_SLICE);
  conv2d_kernel<<<64, 128, 0, stream>>>(f_all + 3 * F_SLICE, w2d45 + 2304,
                                        b2d45 + 16, f_all + 4 * F_SLICE);

  sp_prep_kernel<<<dim3(64, 5), 128, 0, stream>>>(
      f_all, x_t, seg_w, seg_b, sp_wa, sp_ba, sp_wb, sp_bb, sp_sw, sp_sb,
      sp_sd);
  fuse_kernel<<<4, 256, 0, stream>>>(f_all, sp_sd, so_w, so_b, fpar,
                                     (float*)d_out);
}

// Round 2
// 1498.294 us; speedup vs baseline: 1.2729x; 1.2729x over previous
//
#include <hip/hip_runtime.h>
#include <hip/hip_bf16.h>

// ---------------------------------------------------------------------------
// Segment_3DCenter: fp32 implementation, round 2.
// Layouts:
//   x_t    [b][p][d]        (64,121,128)
//   sa_t   [b][oc][p][d]    (64,16,121,128)  conv3d outputs (bufA/bufB)
//   f_all  [i][b][oc][p]    (5,64,16,121)
//   wrep23 [conv2][g2][ic16][kd7][kh3][o8][kw3]   repacked conv weights
//   wrep1  [g2][kd7][kh3][o8][kw3]
// conv3d: block = (b, h, w-quad); 4 waves = (d-half) x (oc-group of 8);
// each thread: acc[8 oc][4 pix]; weights via batched wave-uniform s_loads;
// cpr (softmax-weighted d-reduction) fused into the epilogue.
// ---------------------------------------------------------------------------

#define F_SLICE (64 * 16 * 121)  // 123904

// ---------------- transpose x: [b][c][p] -> [b][p][c], LDS-tiled -----------
__global__ __launch_bounds__(256) void transpose_kernel(
    const float* __restrict__ x, float* __restrict__ x_t) {
  __shared__ float tile[128][123];  // pad 121->123 (gcd(123,32)=1)
  int b = blockIdx.x, t = threadIdx.x;
  const float* xb = x + (size_t)b * 128 * 121;
  for (int idx = t; idx < 128 * 121; idx += 256) {
    int c = idx / 121, p = idx - c * 121;
    tile[c][p] = xb[idx];
  }
  __syncthreads();
  float* ob = x_t + (size_t)b * 121 * 128;
  for (int idx = t; idx < 121 * 128; idx += 256) {
    int p = idx >> 7, c = idx & 127;
    ob[idx] = tile[c][p];
  }
}

// ---------------- softmax over last dim of cpr_w (48 rows x 128) -----------
__global__ __launch_bounds__(128) void softmax_kernel(
    const float* __restrict__ w, float* __restrict__ a) {
  int row = blockIdx.x, t = threadIdx.x;
  __shared__ float red[128];
  float v = w[row * 128 + t];
  red[t] = v;
  __syncthreads();
  for (int s = 64; s; s >>= 1) {
    if (t < s) red[t] = fmaxf(red[t], red[t + s]);
    __syncthreads();
  }
  float m = red[0];
  __syncthreads();
  float e = expf(v - m);
  red[t] = e;
  __syncthreads();
  for (int s = 64; s; s >>= 1) {
    if (t < s) red[t] += red[t + s];
    __syncthreads();
  }
  a[row * 128 + t] = e / red[0];
}

// ---------------- repack conv3d weights for batched scalar loads -----------
__global__ __launch_bounds__(256) void repack_kernel(
    const float* __restrict__ w3d1, const float* __restrict__ w3d23,
    float* __restrict__ wrep1, float* __restrict__ wrep23) {
  int idx = blockIdx.x * 256 + threadIdx.x;
  if (idx < 32256) {
    int r = idx;
    int kw = r % 3; r /= 3;
    int o = r % 8; r /= 8;
    int kh = r % 3; r /= 3;
    int kd = r % 7; r /= 7;
    int ic = r % 16; r /= 16;
    int gg = r % 2; r /= 2;
    int cv = r;
    int oc = gg * 8 + o;
    wrep23[idx] = w3d23[((cv * 16 + oc) * 16 + ic) * 63 + kd * 9 + kh * 3 + kw];
  } else if (idx < 32256 + 1008) {
    int r = idx - 32256;
    int j = r;
    int kw = j % 3; j /= 3;
    int o = j % 8; j /= 8;
    int kh = j % 3; j /= 3;
    int kd = j % 7; j /= 7;
    int gg = j;
    wrep1[r] = w3d1[(gg * 8 + o) * 63 + kd * 9 + kh * 3 + kw];
  }
}

// ---------------- conv3d (7x3x3, pad 3/1/1) + bias + relu + fused cpr ------
template <int IC>
__global__ __launch_bounds__(256, 4) void conv3d_kernel(
    const float* __restrict__ in, const float* __restrict__ wrep,
    const float* __restrict__ bias, const float* __restrict__ al,
    float* __restrict__ outp, float* __restrict__ f_out) {
  constexpr int ICC = (IC == 16) ? 4 : 1;
  __shared__ float in_lds[ICC][18][134];  // [ic][3h x 6w][dpad]
  __shared__ float red[2][16][4];
  const int t = threadIdx.x;
  const int bx = blockIdx.x;  // 0..32
  const int b = blockIdx.y;
  const int h = bx / 3;
  const int w0 = (bx % 3) * 4;
  const int lane = t & 63;
  const int wv = t >> 6;
  const int dh = wv & 1;
  const int dd = lane + (dh << 6);  // 0..127
  const int g = __builtin_amdgcn_readfirstlane(wv >> 1);
  const int oc_base = g << 3;

  float acc[8][4];
#pragma unroll
  for (int o = 0; o < 8; ++o)
#pragma unroll
    for (int c = 0; c < 4; ++c) acc[o][c] = 0.f;

  const int ds = t & 127;
  const int half = t >> 7;

  for (int ic0 = 0; ic0 < IC; ic0 += ICC) {
    __syncthreads();
    // stage ICC*18 rows of 134 (depth-pad 3 each side, zeros outside image)
    for (int r = half; r < ICC * 18; r += 2) {
      int ic = r / 18;
      int sp = r - ic * 18;
      int hr = sp / 6;
      int wc = sp - hr * 6;
      int hh = h - 1 + hr;
      int ww = w0 - 1 + wc;
      bool ok = (hh >= 0) & (hh < 11) & (ww >= 0) & (ww < 11);
      const float* src =
          in + (((size_t)b * IC + ic0 + ic) * 121 + hh * 11 + ww) * 128;
      float v = 0.f;
      if (ok && ds >= 3) v = src[ds - 3];
      in_lds[ic][sp][ds] = v;
      if (ds < 6) {
        float v2 = 0.f;
        if (ok && ds < 3) v2 = src[125 + ds];
        in_lds[ic][sp][128 + ds] = v2;
      }
    }
    __syncthreads();
    for (int ic = 0; ic < ICC; ++ic) {  // runtime loop: keep body in I$
      const float* wbase = wrep + (size_t)(g * IC + ic0 + ic) * 7 * 72;
#pragma unroll
      for (int kd = 0; kd < 7; ++kd) {
#pragma unroll
        for (int kh = 0; kh < 3; ++kh) {
          // 24 wave-uniform weights -> batched s_loads
          float ws[24];
          const float* wp = wbase + kd * 72 + kh * 24;
#pragma unroll
          for (int j = 0; j < 24; ++j) ws[j] = wp[j];
          // 6 LDS reads feed 96 FMAs
          float v[6];
#pragma unroll
          for (int q = 0; q < 6; ++q) v[q] = in_lds[ic][kh * 6 + q][dd + kd];
#pragma unroll
          for (int o = 0; o < 8; ++o)
#pragma unroll
            for (int kw = 0; kw < 3; ++kw) {
              float wv_ = ws[o * 3 + kw];
#pragma unroll
              for (int c = 0; c < 4; ++c)
                acc[o][c] = fmaf(wv_, v[kw + c], acc[o][c]);
            }
        }
      }
    }
  }

  // epilogue: bias+relu, store sa, fused cpr reduction over d
  const int p0 = h * 11 + w0;
  float alv[8];
#pragma unroll
  for (int o = 0; o < 8; ++o) alv[o] = al[(oc_base + o) * 128 + dd];
#pragma unroll
  for (int o = 0; o < 8; ++o) {
    float bv = bias[oc_base + o];
#pragma unroll
    for (int c = 0; c < 4; ++c) {
      float sv = fmaxf(acc[o][c] + bv, 0.f);
      if (w0 + c < 11)
        outp[(((size_t)b * 16 + oc_base + o) * 121 + p0 + c) * 128 + dd] = sv;
      float pv = sv * alv[o];
#pragma unroll
      for (int off = 32; off; off >>= 1) pv += __shfl_down(pv, off, 64);
      if (lane == 0) red[dh][oc_base + o][c] = pv;
    }
  }
  __syncthreads();
  if (t < 64) {
    int oc = t >> 2, c = t & 3;
    if (w0 + c < 11)
      f_out[((size_t)b * 16 + oc) * 121 + p0 + c] =
          fmaxf(red[0][oc][c] + red[1][oc][c], 0.f);
  }
}

// ---------------- both 16->16 2D convs (3x3 pad1 + relu), fused ------------
__global__ __launch_bounds__(128) void conv2d2_kernel(
    const float* __restrict__ fin, const float* __restrict__ wgt,
    const float* __restrict__ bias, float* __restrict__ f4,
    float* __restrict__ f5) {
  const int b = blockIdx.x, t = threadIdx.x;
  __shared__ float buf0[16 * 121];
  __shared__ float buf1[16 * 121];
  const float* fb = fin + (size_t)b * 16 * 121;
  for (int idx = t; idx < 16 * 121; idx += 128) buf0[idx] = fb[idx];
  __syncthreads();
  for (int layer = 0; layer < 2; ++layer) {
    const float* src = layer ? buf1 : buf0;
    float* dst = layer ? nullptr : buf1;
    const float* wl = wgt + layer * 2304;
    const float* bl = bias + layer * 16;
    float* go = (layer ? f5 : f4) + (size_t)b * 16 * 121;
    if (t < 121) {
      int h = t / 11, w = t - h * 11;
      float acc[16];
#pragma unroll
      for (int o = 0; o < 16; ++o) acc[o] = bl[o];
      for (int ic = 0; ic < 16; ++ic) {
#pragma unroll
        for (int u = 0; u < 3; ++u) {
          int hh = h + u - 1;
#pragma unroll
          for (int v = 0; v < 3; ++v) {
            int ww = w + v - 1;
            float val = (hh >= 0 && hh < 11 && ww >= 0 && ww < 11)
                            ? src[ic * 121 + hh * 11 + ww]
                            : 0.f;
            const float* wp = wl + ic * 9 + u * 3 + v;
#pragma unroll
            for (int o = 0; o < 16; ++o)
              acc[o] = fmaf(val, wp[o * 144], acc[o]);
          }
        }
      }
#pragma unroll
      for (int o = 0; o < 16; ++o) {
        float r = fmaxf(acc[o], 0.f);
        go[o * 121 + t] = r;
        if (dst) dst[o * 121 + t] = r;
      }
    }
    __syncthreads();
  }
}

// ---------------- sp path: seg conv -> top5 -> patch convs -> side ---------
__global__ __launch_bounds__(128) void sp_prep_kernel(
    const float* __restrict__ f_all, const float* __restrict__ x_t,
    const float* __restrict__ seg_w, const float* __restrict__ seg_b,
    const float* __restrict__ sp_wa, const float* __restrict__ sp_ba,
    const float* __restrict__ sp_wb, const float* __restrict__ sp_bb,
    const float* __restrict__ sp_sw, const float* __restrict__ sp_sb,
    float* __restrict__ sp_sd) {
  const int b = blockIdx.x, i = blockIdx.y;
  const int t = threadIdx.x;
  __shared__ float fl[16 * 121];
  __shared__ float act[121];
  __shared__ float diffs[121];
  __shared__ int sel[5];
  __shared__ float s7[7], xc7[7];
  __shared__ float P[2][7][7];
  __shared__ float y1[16][9];
  __shared__ float y2[16];

  const float* fb = f_all + ((size_t)i * 64 + b) * 16 * 121;
  for (int idx = t; idx < 16 * 121; idx += 128) fl[idx] = fb[idx];
  __syncthreads();

  if (t < 121) {
    int h = t / 11, w = t - h * 11;
    float a = seg_b[i];
    const float* sw = seg_w + i * 144;
#pragma unroll
    for (int u = 0; u < 3; ++u) {
      int hh = h + u - 1;
#pragma unroll
      for (int v = 0; v < 3; ++v) {
        int ww = w + v - 1;
        if (hh >= 0 && hh < 11 && ww >= 0 && ww < 11) {
          int pp = hh * 11 + ww;
          for (int ic = 0; ic < 16; ++ic)
            a = fmaf(fl[ic * 121 + pp], sw[ic * 9 + u * 3 + v], a);
        }
      }
    }
    act[t] = a;
  }
  __syncthreads();
  if (t < 121) diffs[t] = fabsf(act[t] - act[60]);
  __syncthreads();

  for (int k = 0; k < 5; ++k) {
    if (t < 64) {
      float d0 = diffs[t];
      int i0 = t;
      float d1 = (t + 64 < 121) ? diffs[t + 64] : 3.0e38f;
      if (d1 < d0) { d0 = d1; i0 = t + 64; }
#pragma unroll
      for (int off = 32; off; off >>= 1) {
        float od = __shfl_down(d0, off, 64);
        int oi = __shfl_down(i0, off, 64);
        if (od < d0 || (od == d0 && oi < i0)) { d0 = od; i0 = oi; }
      }
      if (t == 0) {
        sel[k] = i0;
        diffs[i0] = 3.0e38f;
      }
    }
    __syncthreads();
  }

  if (t < 7) {
    const float* xb = x_t + (size_t)b * 121 * 128;
    float s = 0.f;
    for (int k = 0; k < 5; ++k) s += xb[(size_t)sel[k] * 128 + 61 + t];
    s7[t] = s;
    xc7[t] = xb[60 * 128 + 61 + t];
  }
  __syncthreads();
  if (t < 49) {
    int r = t / 7, c = t - r * 7;
    float d0 = s7[c];
    if (fabsf(d0) < 0.01f) d0 = 0.01f;
    float d1 = xc7[c];
    if (fabsf(d1) < 0.01f) d1 = 0.01f;
    P[0][r][c] = s7[r] / d0;
    P[1][r][c] = xc7[r] / d1;
  }
  __syncthreads();
  for (int item = t; item < 144; item += 128) {
    int ch = item / 9, pos = item - ch * 9;
    int a0 = pos / 3, b0 = pos - a0 * 3;
    float a = sp_ba[i * 16 + ch];
    const float* wa = sp_wa + ((size_t)(i * 16 + ch) * 2) * 9;
#pragma unroll
    for (int icc = 0; icc < 2; ++icc)
#pragma unroll
      for (int u = 0; u < 3; ++u)
#pragma unroll
        for (int v = 0; v < 3; ++v)
          a = fmaf(P[icc][2 * a0 + u][2 * b0 + v], wa[icc * 9 + u * 3 + v], a);
    y1[ch][pos] = fmaxf(a, 0.f);
  }
  __syncthreads();
  if (t < 16) {
    float a = sp_bb[i * 16 + t];
    const float* wb = sp_wb + (size_t)(i * 16 + t) * 16 * 9;
    for (int ch = 0; ch < 16; ++ch)
#pragma unroll
      for (int pos = 0; pos < 9; ++pos)
        a = fmaf(y1[ch][pos], wb[ch * 9 + pos], a);
    y2[t] = fmaxf(a, 0.f);
  }
  __syncthreads();
  if (t < 16) {
    float a = sp_sb[i * 16 + t];
    const float* swp = sp_sw + (size_t)(i * 16 + t) * 16;
    for (int ch = 0; ch < 16; ++ch) a = fmaf(y2[ch], swp[ch], a);
    sp_sd[((size_t)i * 64 + b) * 16 + t] = a;
  }
}

// ---------------- final fuse -----------------------------------------------
__global__ __launch_bounds__(256) void fuse_kernel(
    const float* __restrict__ f_all, const float* __restrict__ sp_sd,
    const float* __restrict__ so_w, const float* __restrict__ so_b,
    const float* __restrict__ fp, float* __restrict__ out) {
  int g = blockIdx.x * 256 + threadIdx.x;
  if (g >= 1024) return;
  int b = g >> 4, o = g & 15;
  float tot = 0.f;
  for (int i = 0; i < 5; ++i) {
    float s = so_b[i * 16 + o];
    for (int c = 0; c < 16; ++c)
      s += f_all[(((size_t)i * 64 + b) * 16 + c) * 121 + 60] *
           so_w[(i * 16 + o) * 16 + c];
    tot += fp[i] * s;
    tot += fp[5 + i] * sp_sd[((size_t)i * 64 + b) * 16 + o];
  }
  out[g] = tot;
}

extern "C" void kernel_launch(void* const* d_in, const int* in_sizes, int n_in,
                              void* d_out, int out_size, void* d_ws,
                              size_t ws_size, hipStream_t stream) {
  const float* x = (const float*)d_in[0];
  const float* w3d1 = (const float*)d_in[1];
  const float* b3d1 = (const float*)d_in[2];
  const float* w3d23 = (const float*)d_in[3];
  const float* b3d23 = (const float*)d_in[4];
  const float* cpr_w = (const float*)d_in[5];
  const float* w2d45 = (const float*)d_in[6];
  const float* b2d45 = (const float*)d_in[7];
  const float* seg_w = (const float*)d_in[8];
  const float* seg_b = (const float*)d_in[9];
  const float* so_w = (const float*)d_in[10];
  const float* so_b = (const float*)d_in[11];
  const float* sp_wa = (const float*)d_in[12];
  const float* sp_ba = (const float*)d_in[13];
  const float* sp_wb = (const float*)d_in[14];
  const float* sp_bb = (const float*)d_in[15];
  const float* sp_sw = (const float*)d_in[16];
  const float* sp_sb = (const float*)d_in[17];
  const float* fpar = (const float*)d_in[18];

  float* ws = (float*)d_ws;
  float* x_t = ws;                      // 991232
  float* bufA = x_t + 991232;           // 15859712
  float* bufB = bufA + 15859712;        // 15859712
  float* a_sm = bufB + 15859712;        // 6144
  float* f_all = a_sm + 6144;           // 619520
  float* sp_sd = f_all + 619520;        // 5120
  float* wrep23 = sp_sd + 5120;         // 32256
  float* wrep1 = wrep23 + 32256;        // 1008

  transpose_kernel<<<64, 256, 0, stream>>>(x, x_t);
  softmax_kernel<<<48, 128, 0, stream>>>(cpr_w, a_sm);
  repack_kernel<<<130, 256, 0, stream>>>(w3d1, w3d23, wrep1, wrep23);

  conv3d_kernel<1><<<dim3(33, 64), 256, 0, stream>>>(x_t, wrep1, b3d1, a_sm,
                                                     bufA, f_all);
  conv3d_kernel<16><<<dim3(33, 64), 256, 0, stream>>>(
      bufA, wrep23, b3d23, a_sm + 2048, bufB, f_all + F_SLICE);
  conv3d_kernel<16><<<dim3(33, 64), 256, 0, stream>>>(
      bufB, wrep23 + 16128, b3d23 + 16, a_sm + 4096, bufA,
      f_all + 2 * F_SLICE);

  conv2d2_kernel<<<64, 128, 0, stream>>>(f_all + 2 * F_SLICE, w2d45, b2d45,
                                         f_all + 3 * F_SLICE,
                                         f_all + 4 * F_SLICE);

  sp_prep_kernel<<<dim3(64, 5), 128, 0, stream>>>(
      f_all, x_t, seg_w, seg_b, sp_wa, sp_ba, sp_wb, sp_bb, sp_sw, sp_sb,
      sp_sd);
  fuse_kernel<<<4, 256, 0, stream>>>(f_all, sp_sd, so_w, so_b, fpar,
                                     (float*)d_out);
}

// Round 3
// 1324.435 us; speedup vs baseline: 1.4400x; 1.1313x over previous
//
#include <hip/hip_runtime.h>
#include <hip/hip_bf16.h>

// ---------------------------------------------------------------------------
// Segment_3DCenter round 3: conv2/conv3 on MFMA via f16 hi/lo split (x256
// scaling keeps lo-parts normal). Activations between convs stored as packed
// {hi,lo} f16 pairs (u32) with d-halo pre-padded: pk[b][p][d+3 (134)][ic 16].
// conv1 stays fp32-VALU (ic=1, small) but emits pk + fused cpr.
// ---------------------------------------------------------------------------

#define F_SLICE (64 * 16 * 121)  // 123904
#define PK_ELEMS (64 * 121 * 134 * 16)

typedef _Float16 half8 __attribute__((ext_vector_type(8)));
typedef float float4v __attribute__((ext_vector_type(4)));

union HU { _Float16 h; unsigned short u; };

__device__ inline unsigned pack_pair(float sv) {
  float s = sv * 256.f;
  _Float16 hi = (_Float16)s;
  _Float16 lo = (_Float16)(s - (float)hi);
  HU a, c; a.h = hi; c.h = lo;
  return (unsigned)a.u | ((unsigned)c.u << 16);
}

// ---------------- transpose x: [b][c][p] -> [b][p][c], LDS-tiled -----------
__global__ __launch_bounds__(256) void transpose_kernel(
    const float* __restrict__ x, float* __restrict__ x_t) {
  __shared__ float tile[128][123];
  int b = blockIdx.x, t = threadIdx.x;
  const float* xb = x + (size_t)b * 128 * 121;
  for (int idx = t; idx < 128 * 121; idx += 256) {
    int c = idx / 121, p = idx - c * 121;
    tile[c][p] = xb[idx];
  }
  __syncthreads();
  float* ob = x_t + (size_t)b * 121 * 128;
  for (int idx = t; idx < 121 * 128; idx += 256) {
    int p = idx >> 7, c = idx & 127;
    ob[idx] = tile[c][p];
  }
}

// ---------------- softmax over last dim of cpr_w (48 rows x 128) -----------
__global__ __launch_bounds__(128) void softmax_kernel(
    const float* __restrict__ w, float* __restrict__ a) {
  int row = blockIdx.x, t = threadIdx.x;
  __shared__ float red[128];
  float v = w[row * 128 + t];
  red[t] = v;
  __syncthreads();
  for (int s = 64; s; s >>= 1) {
    if (t < s) red[t] = fmaxf(red[t], red[t + s]);
    __syncthreads();
  }
  float m = red[0];
  __syncthreads();
  float e = expf(v - m);
  red[t] = e;
  __syncthreads();
  for (int s = 64; s; s >>= 1) {
    if (t < s) red[t] += red[t + s];
    __syncthreads();
  }
  a[row * 128 + t] = e / red[0];
}

// ---------------- repack conv1 weights (fp32 path) -------------------------
__global__ __launch_bounds__(256) void repack1_kernel(
    const float* __restrict__ w3d1, float* __restrict__ wrep1) {
  int r = blockIdx.x * 256 + threadIdx.x;
  if (r < 1008) {
    int j = r;
    int kw = j % 3; j /= 3;
    int o = j % 8; j /= 8;
    int kh = j % 3; j /= 3;
    int kd = j % 7; j /= 7;
    int gg = j;
    wrep1[r] = w3d1[(gg * 8 + o) * 63 + kd * 9 + kh * 3 + kw];
  }
}

// ---------------- repack conv2/3 weights into MFMA A-frag layout -----------
// arep[cv 2][chunk 32][part 2][lane 64][j 8] f16. k = cell*16 + ic, cell =
// kd*9+kh*3+kw (cell 63 = zero pad). lane: m=oc=lane&15, q=lane>>4,
// cell = 2*chunk + (q>>1), ic = (q&1)*8 + j. Weights scaled x256.
__global__ __launch_bounds__(256) void arep_kernel(
    const float* __restrict__ w3d23, unsigned short* __restrict__ arep) {
  int idx = blockIdx.x * 256 + threadIdx.x;  // 0..65535
  int j = idx & 7;
  int lane = (idx >> 3) & 63;
  int part = (idx >> 9) & 1;
  int chunk = (idx >> 10) & 31;
  int cv = idx >> 15;
  int m = lane & 15, qq = lane >> 4;
  int e = chunk * 2 + (qq >> 1);
  int ic = (qq & 1) * 8 + j;
  float w = 0.f;
  if (e < 63) {
    int kd = e / 9, kh = (e % 9) / 3, kw = e % 3;
    w = w3d23[((cv * 16 + m) * 16 + ic) * 63 + kd * 9 + kh * 3 + kw] * 256.f;
  }
  _Float16 hi = (_Float16)w;
  HU out;
  out.h = (part == 0) ? hi : (_Float16)(w - (float)hi);
  arep[idx] = out.u;
}

// ---------------- zero the d-halo pads of pk1/pk2 --------------------------
__global__ __launch_bounds__(256) void zeropad_kernel(
    unsigned int* __restrict__ pk1, unsigned int* __restrict__ pk2) {
  int u = blockIdx.x * 256 + threadIdx.x;
  if (u >= 371712) return;
  int q4 = u & 3; u >>= 2;
  int pad = u % 6; u /= 6;
  int p = u % 121; u /= 121;
  int b = u % 64;
  int buf = u / 64;
  int pkd = (pad < 3) ? pad : (128 + pad);
  unsigned int* dst =
      (buf ? pk2 : pk1) + (((size_t)b * 121 + p) * 134 + pkd) * 16 + q4 * 4;
  uint4 z = {0u, 0u, 0u, 0u};
  *(uint4*)dst = z;
}

// ---------------- conv1 (ic=1) fp32: x_t -> pk1 (+fused cpr f1) ------------
__global__ __launch_bounds__(256, 4) void conv1_kernel(
    const float* __restrict__ in, const float* __restrict__ wrep,
    const float* __restrict__ bias, const float* __restrict__ al,
    unsigned int* __restrict__ pkout, float* __restrict__ f_out) {
  __shared__ float in_lds[18][134];
  __shared__ float red[2][16][4];
  const int t = threadIdx.x;
  const int bx = blockIdx.x;
  const int b = blockIdx.y;
  const int h = bx / 3;
  const int w0 = (bx % 3) * 4;
  const int lane = t & 63;
  const int wv = t >> 6;
  const int dh = wv & 1;
  const int dd = lane + (dh << 6);
  const int g = __builtin_amdgcn_readfirstlane(wv >> 1);
  const int oc_base = g << 3;

  float acc[8][4];
#pragma unroll
  for (int o = 0; o < 8; ++o)
#pragma unroll
    for (int c = 0; c < 4; ++c) acc[o][c] = 0.f;

  const int ds = t & 127;
  const int half = t >> 7;

  for (int r = half; r < 18; r += 2) {
    int hr = r / 6;
    int wc = r - hr * 6;
    int hh = h - 1 + hr;
    int ww = w0 - 1 + wc;
    bool ok = (hh >= 0) & (hh < 11) & (ww >= 0) & (ww < 11);
    const float* src = in + (((size_t)b) * 121 + hh * 11 + ww) * 128;
    float v = 0.f;
    if (ok && ds >= 3) v = src[ds - 3];
    in_lds[r][ds] = v;
    if (ds < 6) {
      float v2 = 0.f;
      if (ok && ds < 3) v2 = src[125 + ds];
      in_lds[r][128 + ds] = v2;
    }
  }
  __syncthreads();
  const float* wbase = wrep + g * 504;
#pragma unroll
  for (int kd = 0; kd < 7; ++kd) {
#pragma unroll
    for (int kh = 0; kh < 3; ++kh) {
      float ws[24];
      const float* wp = wbase + kd * 72 + kh * 24;
#pragma unroll
      for (int j = 0; j < 24; ++j) ws[j] = wp[j];
      float v[6];
#pragma unroll
      for (int qq = 0; qq < 6; ++qq) v[qq] = in_lds[kh * 6 + qq][dd + kd];
#pragma unroll
      for (int o = 0; o < 8; ++o)
#pragma unroll
        for (int kw = 0; kw < 3; ++kw) {
          float wv_ = ws[o * 3 + kw];
#pragma unroll
          for (int c = 0; c < 4; ++c)
            acc[o][c] = fmaf(wv_, v[kw + c], acc[o][c]);
        }
    }
  }

  const int p0 = h * 11 + w0;
  float alv[8];
#pragma unroll
  for (int o = 0; o < 8; ++o) alv[o] = al[(oc_base + o) * 128 + dd];
#pragma unroll
  for (int o = 0; o < 8; ++o) {
    float bv = bias[oc_base + o];
#pragma unroll
    for (int c = 0; c < 4; ++c) {
      float sv = fmaxf(acc[o][c] + bv, 0.f);
      if (w0 + c < 11)
        pkout[(((size_t)b * 121 + p0 + c) * 134 + dd + 3) * 16 + oc_base + o] =
            pack_pair(sv);
      float pv = sv * alv[o];
#pragma unroll
      for (int off = 32; off; off >>= 1) pv += __shfl_down(pv, off, 64);
      if (lane == 0) red[dh][oc_base + o][c] = pv;
    }
  }
  __syncthreads();
  if (t < 64) {
    int oc = t >> 2, c = t & 3;
    if (w0 + c < 11)
      f_out[((size_t)b * 16 + oc) * 121 + p0 + c] =
          fmaxf(red[0][oc][c] + red[1][oc][c], 0.f);
  }
}

// ---------------- conv2/conv3: MFMA f16x2-split ----------------------------
// Block = (h, b), 4 waves; wave owns w-triple {3w..3w+2} (w=11 dummy).
// Loops d16 = 0..7; per d16 stages [3 kh-rows][14 w-cols][22 d][16 ic] as
// separate hi/lo f16 planes: lds[part][panel 42][ich 2][d 22][ic8].
// Per K-chunk (2 cells x 16 ic): A-frags (hi,lo) from global (pre-repacked),
// B-frags one conflict-free ds_read_b128 each; 3 MFMAs (hh, h*lo, lo*h).
template <bool WRITE_PK>
__global__ __launch_bounds__(256, 2) void conv_mfma_kernel(
    const unsigned int* __restrict__ pkin,
    const unsigned short* __restrict__ arep, const float* __restrict__ bias,
    const float* __restrict__ al, unsigned int* __restrict__ pkout,
    float* __restrict__ f_out) {
  __shared__ _Float16 lds2[2][14784];  // part stride 42*352
  const int t = threadIdx.x;
  const int h = blockIdx.x, b = blockIdx.y;
  const int lane = t & 63, wave = t >> 6;
  const int n = lane & 15, q = lane >> 4;

  // staging descriptors: 3696 uint4-units = 42 panels x 22 d x 4 ic-quads
  int gbase[15], lbase[15];
#pragma unroll
  for (int i = 0; i < 15; ++i) {
    int u = t + i * 256;
    if (u < 3696) {
      int q4 = u & 3;
      int rem = u >> 2;
      int panel = rem / 22;
      int dd = rem - panel * 22;
      int r = panel / 14;
      int cc = panel - r * 14;
      int hh = h + r - 1, ww = cc - 1;
      bool ok = (hh >= 0) & (hh < 11) & (ww >= 0) & (ww < 11);
      lbase[i] = (panel * 2 + (q4 >> 1)) * 176 + dd * 8 + (q4 & 1) * 4;
      gbase[i] = ok ? (((b * 121 + hh * 11 + ww) * 134 + dd) * 16 + q4 * 4)
                    : -1;
    } else {
      lbase[i] = -1;
      gbase[i] = -1;
    }
  }
  // zero invalid units once (both parts); valid units overwritten per d16
#pragma unroll
  for (int i = 0; i < 15; ++i) {
    if (lbase[i] >= 0 && gbase[i] < 0) {
      uint2 z; z.x = 0u; z.y = 0u;
      *(uint2*)&lds2[0][lbase[i]] = z;
      *(uint2*)&lds2[1][lbase[i]] = z;
    }
  }

  float bias_r[4];
#pragma unroll
  for (int r = 0; r < 4; ++r) bias_r[r] = bias[q * 4 + r];

  const int bbase = (q & 1) * 176 + n * 8;  // per-lane B base (u16 units)
  float facc[3][4];
#pragma unroll
  for (int tt = 0; tt < 3; ++tt)
#pragma unroll
    for (int r = 0; r < 4; ++r) facc[tt][r] = 0.f;

  for (int d16 = 0; d16 < 8; ++d16) {
    __syncthreads();
    // stage this d-window
#pragma unroll
    for (int i = 0; i < 15; ++i) {
      if (gbase[i] >= 0) {
        uint4 v = *(const uint4*)&pkin[gbase[i] + d16 * 256];
        uint2 hv, lv;
        hv.x = (v.x & 0xffffu) | (v.y << 16);
        hv.y = (v.z & 0xffffu) | (v.w << 16);
        lv.x = (v.x >> 16) | (v.y & 0xffff0000u);
        lv.y = (v.z >> 16) | (v.w & 0xffff0000u);
        *(uint2*)&lds2[0][lbase[i]] = hv;
        *(uint2*)&lds2[1][lbase[i]] = lv;
      }
    }
    __syncthreads();

    float4v acc[3];
#pragma unroll
    for (int tt = 0; tt < 3; ++tt) acc[tt] = (float4v){0.f, 0.f, 0.f, 0.f};

#pragma unroll
    for (int c = 0; c < 32; ++c) {
      const int e0 = 2 * c, e1r = 2 * c + 1;
      const int e0c = (e0 > 62) ? 62 : e0;
      const int e1 = (e1r > 62) ? 62 : e1r;
      const int pan0 = ((e0c % 9) / 3) * 14 + (e0c % 3);
      const int pan1 = ((e1 % 9) / 3) * 14 + (e1 % 3);
      const int sel0 = pan0 * 352 + (e0c / 9) * 8;
      const int sel1 = pan1 * 352 + (e1 / 9) * 8;
      const int sel = (lane & 32) ? sel1 : sel0;
      half8 ahi = *(const half8*)&arep[((c * 2 + 0) * 64 + lane) * 8];
      half8 alo = *(const half8*)&arep[((c * 2 + 1) * 64 + lane) * 8];
#pragma unroll
      for (int tt = 0; tt < 3; ++tt) {
        const int wl = wave * 3 + tt;
        const _Float16* ph = &lds2[0][bbase + sel + wl * 352];
        half8 bhi = *(const half8*)ph;
        half8 blo = *(const half8*)(ph + 14784);
        acc[tt] = __builtin_amdgcn_mfma_f32_16x16x32_f16(ahi, bhi, acc[tt], 0, 0, 0);
        acc[tt] = __builtin_amdgcn_mfma_f32_16x16x32_f16(ahi, blo, acc[tt], 0, 0, 0);
        acc[tt] = __builtin_amdgcn_mfma_f32_16x16x32_f16(alo, bhi, acc[tt], 0, 0, 0);
      }
    }

    // epilogue for this d16
#pragma unroll
    for (int tt = 0; tt < 3; ++tt) {
      const int wl = wave * 3 + tt;
      if (wl < 11) {
        const int p = h * 11 + wl;
        uint4 pkv;
        unsigned pkarr[4];
#pragma unroll
        for (int r = 0; r < 4; ++r) {
          float sv = fmaxf(acc[tt][r] * (1.f / 65536.f) + bias_r[r], 0.f);
          if (WRITE_PK) pkarr[r] = pack_pair(sv);
          facc[tt][r] += sv * al[(q * 4 + r) * 128 + d16 * 16 + n];
        }
        if (WRITE_PK) {
          pkv.x = pkarr[0]; pkv.y = pkarr[1]; pkv.z = pkarr[2]; pkv.w = pkarr[3];
          *(uint4*)&pkout[(((size_t)b * 121 + p) * 134 + d16 * 16 + n + 3) * 16 +
                          q * 4] = pkv;
        }
      }
    }
  }

  // fused cpr: reduce over the 16 lanes of each quad-group (d within d16 was
  // accumulated over the d16 loop; n covers the 16 d's of each block)
#pragma unroll
  for (int tt = 0; tt < 3; ++tt) {
    const int wl = wave * 3 + tt;
#pragma unroll
    for (int r = 0; r < 4; ++r) {
      float v = facc[tt][r];
      v += __shfl_xor(v, 1, 64);
      v += __shfl_xor(v, 2, 64);
      v += __shfl_xor(v, 4, 64);
      v += __shfl_xor(v, 8, 64);
      if (n == 0 && wl < 11)
        f_out[((size_t)b * 16 + q * 4 + r) * 121 + h * 11 + wl] =
            fmaxf(v, 0.f);
    }
  }
}

// ---------------- both 16->16 2D convs (3x3 pad1 + relu), fused ------------
__global__ __launch_bounds__(128) void conv2d2_kernel(
    const float* __restrict__ fin, const float* __restrict__ wgt,
    const float* __restrict__ bias, float* __restrict__ f4,
    float* __restrict__ f5) {
  const int b = blockIdx.x, t = threadIdx.x;
  __shared__ float buf0[16 * 121];
  __shared__ float buf1[16 * 121];
  const float* fb = fin + (size_t)b * 16 * 121;
  for (int idx = t; idx < 16 * 121; idx += 128) buf0[idx] = fb[idx];
  __syncthreads();
  for (int layer = 0; layer < 2; ++layer) {
    const float* src = layer ? buf1 : buf0;
    float* dst = layer ? nullptr : buf1;
    const float* wl = wgt + layer * 2304;
    const float* bl = bias + layer * 16;
    float* go = (layer ? f5 : f4) + (size_t)b * 16 * 121;
    if (t < 121) {
      int h = t / 11, w = t - h * 11;
      float acc[16];
#pragma unroll
      for (int o = 0; o < 16; ++o) acc[o] = bl[o];
      for (int ic = 0; ic < 16; ++ic) {
#pragma unroll
        for (int u = 0; u < 3; ++u) {
          int hh = h + u - 1;
#pragma unroll
          for (int v = 0; v < 3; ++v) {
            int ww = w + v - 1;
            float val = (hh >= 0 && hh < 11 && ww >= 0 && ww < 11)
                            ? src[ic * 121 + hh * 11 + ww]
                            : 0.f;
            const float* wp = wl + ic * 9 + u * 3 + v;
#pragma unroll
            for (int o = 0; o < 16; ++o)
              acc[o] = fmaf(val, wp[o * 144], acc[o]);
          }
        }
      }
#pragma unroll
      for (int o = 0; o < 16; ++o) {
        float r = fmaxf(acc[o], 0.f);
        go[o * 121 + t] = r;
        if (dst) dst[o * 121 + t] = r;
      }
    }
    __syncthreads();
  }
}

// ---------------- sp path: seg conv -> top5 -> patch convs -> side ---------
__global__ __launch_bounds__(128) void sp_prep_kernel(
    const float* __restrict__ f_all, const float* __restrict__ x_t,
    const float* __restrict__ seg_w, const float* __restrict__ seg_b,
    const float* __restrict__ sp_wa, const float* __restrict__ sp_ba,
    const float* __restrict__ sp_wb, const float* __restrict__ sp_bb,
    const float* __restrict__ sp_sw, const float* __restrict__ sp_sb,
    float* __restrict__ sp_sd) {
  const int b = blockIdx.x, i = blockIdx.y;
  const int t = threadIdx.x;
  __shared__ float fl[16 * 121];
  __shared__ float act[121];
  __shared__ float diffs[121];
  __shared__ int sel[5];
  __shared__ float s7[7], xc7[7];
  __shared__ float P[2][7][7];
  __shared__ float y1[16][9];
  __shared__ float y2[16];

  const float* fb = f_all + ((size_t)i * 64 + b) * 16 * 121;
  for (int idx = t; idx < 16 * 121; idx += 128) fl[idx] = fb[idx];
  __syncthreads();

  if (t < 121) {
    int h = t / 11, w = t - h * 11;
    float a = seg_b[i];
    const float* sw = seg_w + i * 144;
#pragma unroll
    for (int u = 0; u < 3; ++u) {
      int hh = h + u - 1;
#pragma unroll
      for (int v = 0; v < 3; ++v) {
        int ww = w + v - 1;
        if (hh >= 0 && hh < 11 && ww >= 0 && ww < 11) {
          int pp = hh * 11 + ww;
          for (int ic = 0; ic < 16; ++ic)
            a = fmaf(fl[ic * 121 + pp], sw[ic * 9 + u * 3 + v], a);
        }
      }
    }
    act[t] = a;
  }
  __syncthreads();
  if (t < 121) diffs[t] = fabsf(act[t] - act[60]);
  __syncthreads();

  for (int k = 0; k < 5; ++k) {
    if (t < 64) {
      float d0 = diffs[t];
      int i0 = t;
      float d1 = (t + 64 < 121) ? diffs[t + 64] : 3.0e38f;
      if (d1 < d0) { d0 = d1; i0 = t + 64; }
#pragma unroll
      for (int off = 32; off; off >>= 1) {
        float od = __shfl_down(d0, off, 64);
        int oi = __shfl_down(i0, off, 64);
        if (od < d0 || (od == d0 && oi < i0)) { d0 = od; i0 = oi; }
      }
      if (t == 0) {
        sel[k] = i0;
        diffs[i0] = 3.0e38f;
      }
    }
    __syncthreads();
  }

  if (t < 7) {
    const float* xb = x_t + (size_t)b * 121 * 128;
    float s = 0.f;
    for (int k = 0; k < 5; ++k) s += xb[(size_t)sel[k] * 128 + 61 + t];
    s7[t] = s;
    xc7[t] = xb[60 * 128 + 61 + t];
  }
  __syncthreads();
  if (t < 49) {
    int r = t / 7, c = t - r * 7;
    float d0 = s7[c];
    if (fabsf(d0) < 0.01f) d0 = 0.01f;
    float d1 = xc7[c];
    if (fabsf(d1) < 0.01f) d1 = 0.01f;
    P[0][r][c] = s7[r] / d0;
    P[1][r][c] = xc7[r] / d1;
  }
  __syncthreads();
  for (int item = t; item < 144; item += 128) {
    int ch = item / 9, pos = item - ch * 9;
    int a0 = pos / 3, b0 = pos - a0 * 3;
    float a = sp_ba[i * 16 + ch];
    const float* wa = sp_wa + ((size_t)(i * 16 + ch) * 2) * 9;
#pragma unroll
    for (int icc = 0; icc < 2; ++icc)
#pragma unroll
      for (int u = 0; u < 3; ++u)
#pragma unroll
        for (int v = 0; v < 3; ++v)
          a = fmaf(P[icc][2 * a0 + u][2 * b0 + v], wa[icc * 9 + u * 3 + v], a);
    y1[ch][pos] = fmaxf(a, 0.f);
  }
  __syncthreads();
  if (t < 16) {
    float a = sp_bb[i * 16 + t];
    const float* wb = sp_wb + (size_t)(i * 16 + t) * 16 * 9;
    for (int ch = 0; ch < 16; ++ch)
#pragma unroll
      for (int pos = 0; pos < 9; ++pos)
        a = fmaf(y1[ch][pos], wb[ch * 9 + pos], a);
    y2[t] = fmaxf(a, 0.f);
  }
  __syncthreads();
  if (t < 16) {
    float a = sp_sb[i * 16 + t];
    const float* swp = sp_sw + (size_t)(i * 16 + t) * 16;
    for (int ch = 0; ch < 16; ++ch) a = fmaf(y2[ch], swp[ch], a);
    sp_sd[((size_t)i * 64 + b) * 16 + t] = a;
  }
}

// ---------------- final fuse -----------------------------------------------
__global__ __launch_bounds__(256) void fuse_kernel(
    const float* __restrict__ f_all, const float* __restrict__ sp_sd,
    const float* __restrict__ so_w, const float* __restrict__ so_b,
    const float* __restrict__ fp, float* __restrict__ out) {
  int g = blockIdx.x * 256 + threadIdx.x;
  if (g >= 1024) return;
  int b = g >> 4, o = g & 15;
  float tot = 0.f;
  for (int i = 0; i < 5; ++i) {
    float s = so_b[i * 16 + o];
    for (int c = 0; c < 16; ++c)
      s += f_all[(((size_t)i * 64 + b) * 16 + c) * 121 + 60] *
           so_w[(i * 16 + o) * 16 + c];
    tot += fp[i] * s;
    tot += fp[5 + i] * sp_sd[((size_t)i * 64 + b) * 16 + o];
  }
  out[g] = tot;
}

extern "C" void kernel_launch(void* const* d_in, const int* in_sizes, int n_in,
                              void* d_out, int out_size, void* d_ws,
                              size_t ws_size, hipStream_t stream) {
  const float* x = (const float*)d_in[0];
  const float* w3d1 = (const float*)d_in[1];
  const float* b3d1 = (const float*)d_in[2];
  const float* w3d23 = (const float*)d_in[3];
  const float* b3d23 = (const float*)d_in[4];
  const float* cpr_w = (const float*)d_in[5];
  const float* w2d45 = (const float*)d_in[6];
  const float* b2d45 = (const float*)d_in[7];
  const float* seg_w = (const float*)d_in[8];
  const float* seg_b = (const float*)d_in[9];
  const float* so_w = (const float*)d_in[10];
  const float* so_b = (const float*)d_in[11];
  const float* sp_wa = (const float*)d_in[12];
  const float* sp_ba = (const float*)d_in[13];
  const float* sp_wb = (const float*)d_in[14];
  const float* sp_bb = (const float*)d_in[15];
  const float* sp_sw = (const float*)d_in[16];
  const float* sp_sb = (const float*)d_in[17];
  const float* fpar = (const float*)d_in[18];

  float* ws = (float*)d_ws;
  float* x_t = ws;                       // 991232 f
  float* a_sm = x_t + 991232;            // 6144 f
  float* f_all = a_sm + 6144;            // 619520 f
  float* sp_sd = f_all + 619520;         // 5120 f
  float* wrep1 = sp_sd + 5120;           // 1008 f (+pad)
  unsigned int* pk1 = (unsigned int*)(wrep1 + 1024);  // PK_ELEMS u32
  unsigned int* pk2 = pk1 + PK_ELEMS;                 // PK_ELEMS u32
  unsigned short* arep = (unsigned short*)(pk2 + PK_ELEMS);  // 65536 u16

  transpose_kernel<<<64, 256, 0, stream>>>(x, x_t);
  softmax_kernel<<<48, 128, 0, stream>>>(cpr_w, a_sm);
  repack1_kernel<<<4, 256, 0, stream>>>(w3d1, wrep1);
  arep_kernel<<<256, 256, 0, stream>>>(w3d23, arep);
  zeropad_kernel<<<1452, 256, 0, stream>>>(pk1, pk2);

  conv1_kernel<<<dim3(33, 64), 256, 0, stream>>>(x_t, wrep1, b3d1, a_sm, pk1,
                                                 f_all);
  conv_mfma_kernel<true><<<dim3(11, 64), 256, 0, stream>>>(
      pk1, arep, b3d23, a_sm + 2048, pk2, f_all + F_SLICE);
  conv_mfma_kernel<false><<<dim3(11, 64), 256, 0, stream>>>(
      pk2, arep + 32768, b3d23 + 16, a_sm + 4096, nullptr,
      f_all + 2 * F_SLICE);

  conv2d2_kernel<<<64, 128, 0, stream>>>(f_all + 2 * F_SLICE, w2d45, b2d45,
                                         f_all + 3 * F_SLICE,
                                         f_all + 4 * F_SLICE);

  sp_prep_kernel<<<dim3(64, 5), 128, 0, stream>>>(
      f_all, x_t, seg_w, seg_b, sp_wa, sp_ba, sp_wb, sp_bb, sp_sw, sp_sb,
      sp_sd);
  fuse_kernel<<<4, 256, 0, stream>>>(f_all, sp_sd, so_w, so_b, fpar,
                                     (float*)d_out);
}